// Round 8
// baseline (508.270 us; speedup 1.0000x reference)
//
#include <hip/hip_runtime.h>

// B=8, C=256, H=W=64 -> N=4096, Cq=32. fp32 I/O.
// out = x + attn(x): q=wq x, k=wk x, v=wv x (1x1 conv), softmax over keys (no scale).
//
// v7: occupancy push.
//  - attn: 2 blocks per Q-tile (channel halves) -> 1024 blocks (4/CU);
//    double-buffered P in LDS -> ONE barrier per 32-key chunk;
//    pass 0 (stats) walks K in 64-key chunks.
//  - proj: row-split 320 -> 2x160 -> 1024 blocks (4/CU), 40-VGPR acc, unroll 2.
// MFMA 16x16x32_bf16 layouts (HW-verified): A[m=lane&15][k=quad*8+j],
// B[n=lane&15][k=quad*8+j], C/D: col=lane&15, row=quad*4+reg.

#define CH  256
#define DQ  32
#define NSP 4096
#define RWS 320

typedef short short8 __attribute__((ext_vector_type(8)));
typedef float float4v __attribute__((ext_vector_type(4)));

__device__ __forceinline__ unsigned short f2b(float f) {  // RNE f32->bf16
  unsigned int u = __float_as_uint(f);
  unsigned int r = u + 0x7fffu + ((u >> 16) & 1u);
  return (unsigned short)(r >> 16);
}
__device__ __forceinline__ short8 ld8(const unsigned short* p) {
  return *(const short8*)p;
}

// ---------------------------------------------------------------- prep ------
__global__ __launch_bounds__(256) void prep_kernel(
    const float* __restrict__ wq, const float* __restrict__ bq,
    const float* __restrict__ wk, const float* __restrict__ bk,
    const float* __restrict__ wv, const float* __restrict__ bv,
    float* __restrict__ wall, float* __restrict__ ball) {
  int r = blockIdx.x, c = threadIdx.x;
  float v;
  if (r < 32)       v = wq[r * CH + c];
  else if (r < 64)  v = wk[(r - 32) * CH + c];
  else              v = wv[(r - 64) * CH + c];
  wall[r * CH + c] = v;
  if (c == 0)
    ball[r] = (r < 32) ? bq[r] : (r < 64 ? bk[r - 32] : bv[r - 64]);
}

// ---------------------------------------------------------------- proj ------
// grid (64, 2, ns); block 256. Block: 160 rows x 64 n; thread 10 rows x 4 n.
__global__ __launch_bounds__(256, 4) void proj_kernel(
    const float* __restrict__ x,
    const float* __restrict__ wall, const float* __restrict__ ball,
    unsigned short* __restrict__ qb, unsigned short* __restrict__ kb,
    unsigned short* __restrict__ vb, int b0) {
  const int bz = blockIdx.z;
  const int bg = b0 + bz;
  const int t  = threadIdx.x;
  const int r0 = blockIdx.y * 160 + (t >> 4) * 10;
  const int n  = blockIdx.x * 64 + (t & 15) * 4;
  const float* xp = x + (size_t)bg * CH * NSP + n;

  float acc[10][4];
#pragma unroll
  for (int rr = 0; rr < 10; ++rr) {
    float bias = ball[r0 + rr];
#pragma unroll
    for (int nn = 0; nn < 4; ++nn) acc[rr][nn] = bias;
  }

#pragma unroll 2
  for (int c4 = 0; c4 < CH; c4 += 4) {
    float4 xv[4];
#pragma unroll
    for (int cc = 0; cc < 4; ++cc)
      xv[cc] = *(const float4*)(xp + (size_t)(c4 + cc) * NSP);
#pragma unroll
    for (int rr = 0; rr < 10; ++rr) {
      float4 wr = *(const float4*)(wall + (size_t)(r0 + rr) * CH + c4);
      acc[rr][0] += wr.x * xv[0].x + wr.y * xv[1].x + wr.z * xv[2].x + wr.w * xv[3].x;
      acc[rr][1] += wr.x * xv[0].y + wr.y * xv[1].y + wr.z * xv[2].y + wr.w * xv[3].y;
      acc[rr][2] += wr.x * xv[0].z + wr.y * xv[1].z + wr.z * xv[2].z + wr.w * xv[3].z;
      acc[rr][3] += wr.x * xv[0].w + wr.y * xv[1].w + wr.z * xv[2].w + wr.w * xv[3].w;
    }
  }

#pragma unroll
  for (int rr = 0; rr < 10; ++rr) {
    int r = r0 + rr;
    if (r < 32) {
#pragma unroll
      for (int nn = 0; nn < 4; ++nn)
        qb[((size_t)bz * NSP + n + nn) * DQ + r] = f2b(acc[rr][nn]);
    } else if (r < 64) {
#pragma unroll
      for (int nn = 0; nn < 4; ++nn)
        kb[((size_t)bz * NSP + n + nn) * DQ + (r - 32)] = f2b(acc[rr][nn]);
    } else {
      ushort4 o = {f2b(acc[rr][0]), f2b(acc[rr][1]), f2b(acc[rr][2]), f2b(acc[rr][3])};
      *(ushort4*)&vb[((size_t)bz * CH + (r - 64)) * NSP + n] = o;
    }
  }
}

// ---------------------------------------------------------------- attn ------
// grid (2*64*ns): bl = blockIdx%ns (XCD-pins batch), rest = blockIdx/ns;
// i0 = (rest>>1)*64 Q-rows, ch0 = (rest&1)*128 channel half.
// block 256 = 4 waves; wave w: softmax rows 16w..16w+15, PV channels
// ch0 + [32w, 32w+32). Pass 0: per-lane online (m,l), 64-key chunks, merge at
// end; moff = m*log2e + log2(l). Pass 1 per 32-key chunk: QK MFMA -> p ->
// P to LDS buf cp -> ONE barrier -> pf/vf -> 8 PV MFMAs (double-buffered P).
__global__ __launch_bounds__(256, 4) void attn_kernel(
    const float* __restrict__ x,
    const unsigned short* __restrict__ qb, const unsigned short* __restrict__ kb,
    const unsigned short* __restrict__ vb,
    float* __restrict__ out, int b0, int ns) {
  __shared__ unsigned short ps[2][64][40];  // P bf16, dbuf, row stride 80 B

  const int bl   = blockIdx.x % ns;
  const int bg   = b0 + bl;
  const int rest = blockIdx.x / ns;
  const int i0   = (rest >> 1) * 64;
  const int ch0  = (rest & 1) * 128;
  const int t    = threadIdx.x;
  const int w    = t >> 6;
  const int lane = t & 63;
  const int col  = lane & 15;
  const int quad = lane >> 4;
  const float LOG2E = 1.4426950408889634f;

  const unsigned short* qbb = qb + (size_t)bl * NSP * DQ;
  const unsigned short* kbb = kb + (size_t)bl * NSP * DQ;
  const unsigned short* vbb = vb + (size_t)bl * CH * NSP;

  const short8 qf = ld8(qbb + (size_t)(i0 + 16 * w + col) * DQ + quad * 8);
  const float4v z4 = (float4v){0.f, 0.f, 0.f, 0.f};

  // ---------------- pass 0: per-lane online stats (64-key chunks) ----------
  float m_[4], l_[4];
#pragma unroll
  for (int r = 0; r < 4; ++r) { m_[r] = -3.0e38f; l_[r] = 0.0f; }

  for (int j0 = 0; j0 < NSP; j0 += 64) {
    short8 kf[4];
    float4v cc[4];
#pragma unroll
    for (int u = 0; u < 4; ++u)
      kf[u] = ld8(kbb + (size_t)(j0 + 16 * u + col) * DQ + quad * 8);
#pragma unroll
    for (int u = 0; u < 4; ++u)
      cc[u] = __builtin_amdgcn_mfma_f32_16x16x32_bf16(qf, kf[u], z4, 0, 0, 0);
#pragma unroll
    for (int reg = 0; reg < 4; ++reg) {
      float s0 = cc[0][reg], s1 = cc[1][reg], s2 = cc[2][reg], s3 = cc[3][reg];
      float mx = fmaxf(fmaxf(s0, s1), fmaxf(s2, s3));
      float mn = fmaxf(m_[reg], mx);
      l_[reg] = l_[reg] * __expf(m_[reg] - mn)
              + __expf(s0 - mn) + __expf(s1 - mn)
              + __expf(s2 - mn) + __expf(s3 - mn);
      m_[reg] = mn;
    }
  }
#pragma unroll
  for (int reg = 0; reg < 4; ++reg) {
#pragma unroll
    for (int mask = 1; mask <= 8; mask <<= 1) {
      float mo = __shfl_xor(m_[reg], mask);
      float lo = __shfl_xor(l_[reg], mask);
      float mn = fmaxf(m_[reg], mo);
      l_[reg] = l_[reg] * __expf(m_[reg] - mn) + lo * __expf(mo - mn);
      m_[reg] = mn;
    }
  }
  float moff[4];
#pragma unroll
  for (int reg = 0; reg < 4; ++reg)
    moff[reg] = m_[reg] * LOG2E + __builtin_amdgcn_logf(l_[reg]);

  // ---------------- pass 1: P + PV (one barrier per chunk, dbuf P) ---------
  float4v acc[4][2];  // [row-group][channel-tile]
#pragma unroll
  for (int rg = 0; rg < 4; ++rg)
#pragma unroll
    for (int ct = 0; ct < 2; ++ct) acc[rg][ct] = z4;

  for (int j0 = 0; j0 < NSP; j0 += 32) {
    const int cp = (j0 >> 5) & 1;
    const short8 kf0 = ld8(kbb + (size_t)(j0 + col) * DQ + quad * 8);
    const short8 kf1 = ld8(kbb + (size_t)(j0 + 16 + col) * DQ + quad * 8);
    float4v c0 = __builtin_amdgcn_mfma_f32_16x16x32_bf16(qf, kf0, z4, 0, 0, 0);
    float4v c1 = __builtin_amdgcn_mfma_f32_16x16x32_bf16(qf, kf1, z4, 0, 0, 0);
#pragma unroll
    for (int reg = 0; reg < 4; ++reg) {
      int row = 16 * w + quad * 4 + reg;
      float p0 = __builtin_amdgcn_exp2f(fmaf(c0[reg], LOG2E, -moff[reg]));
      float p1 = __builtin_amdgcn_exp2f(fmaf(c1[reg], LOG2E, -moff[reg]));
      ps[cp][row][col]      = f2b(p0);
      ps[cp][row][col + 16] = f2b(p1);
    }
    __syncthreads();   // P(cp) visible; reads of buf cp from 2 chunks ago done

    short8 pf[4];
#pragma unroll
    for (int rg = 0; rg < 4; ++rg)
      pf[rg] = *(const short8*)&ps[cp][rg * 16 + col][quad * 8];

#pragma unroll
    for (int ct = 0; ct < 2; ++ct) {
      int c = ch0 + (w * 2 + ct) * 16 + col;
      const short8 vf = ld8(vbb + (size_t)c * NSP + j0 + quad * 8);
#pragma unroll
      for (int rg = 0; rg < 4; ++rg)
        acc[rg][ct] = __builtin_amdgcn_mfma_f32_16x16x32_bf16(pf[rg], vf, acc[rg][ct], 0, 0, 0);
    }
  }

  // ---------------- epilogue: residual + store (already normalized) --------
#pragma unroll
  for (int rg = 0; rg < 4; ++rg) {
#pragma unroll
    for (int ct = 0; ct < 2; ++ct) {
      int c  = ch0 + (w * 2 + ct) * 16 + col;
      int ib = i0 + rg * 16 + quad * 4;
      size_t idx = ((size_t)bg * CH + c) * NSP + ib;
      float4 xr = *(const float4*)&x[idx];
      float4 o;
      o.x = acc[rg][ct][0] + xr.x;
      o.y = acc[rg][ct][1] + xr.y;
      o.z = acc[rg][ct][2] + xr.z;
      o.w = acc[rg][ct][3] + xr.w;
      *(float4*)&out[idx] = o;
    }
  }
}

// ---------------------------------------------------------------- launch ----
extern "C" void kernel_launch(void* const* d_in, const int* in_sizes, int n_in,
                              void* d_out, int out_size, void* d_ws, size_t ws_size,
                              hipStream_t stream) {
  (void)in_sizes; (void)n_in; (void)out_size;
  const float* x  = (const float*)d_in[0];
  const float* wq = (const float*)d_in[1];
  const float* bq = (const float*)d_in[2];
  const float* wk = (const float*)d_in[3];
  const float* bk = (const float*)d_in[4];
  const float* wv = (const float*)d_in[5];
  const float* bv = (const float*)d_in[6];
  float* out = (float*)d_out;

  const size_t WALL_B = (size_t)RWS * CH * sizeof(float) + 4096;  // wall+ball
  const size_t QB_B = (size_t)NSP * DQ * sizeof(unsigned short);  // 256 KiB
  const size_t VB_B = (size_t)CH * NSP * sizeof(unsigned short);  //   2 MiB
  const size_t PER_B = 2 * QB_B + VB_B;                           // 2.5 MiB/batch

  int ns = 8;
  while (ns > 1 && WALL_B + (size_t)ns * PER_B > ws_size) ns >>= 1;

  char* ws = (char*)d_ws;
  float* wall = (float*)ws;
  float* ball = (float*)(ws + (size_t)RWS * CH * sizeof(float));
  char* qkv = ws + WALL_B;
  unsigned short* qb = (unsigned short*)qkv;
  unsigned short* kb = (unsigned short*)(qkv + (size_t)ns * QB_B);
  unsigned short* vb = (unsigned short*)(qkv + (size_t)ns * 2 * QB_B);

  prep_kernel<<<dim3(RWS), dim3(256), 0, stream>>>(wq, bq, wk, bk, wv, bv, wall, ball);
  for (int b0 = 0; b0 < 8; b0 += ns) {
    proj_kernel<<<dim3(64, 2, ns), dim3(256), 0, stream>>>(
        x, wall, ball, qb, kb, vb, b0);
    attn_kernel<<<dim3(2 * 64 * ns), dim3(256), 0, stream>>>(
        x, qb, kb, vb, out, b0, ns);
  }
}

// Round 9
// 360.245 us; speedup vs baseline: 1.4109x; 1.4109x over previous
//
#include <hip/hip_runtime.h>

// B=8, C=256, H=W=64 -> N=4096, Cq=32. fp32 I/O.
// out = x + attn(x): q=wq x, k=wk x, v=wv x (1x1 conv), softmax over keys (no scale).
//
// v8: 512-thread attn blocks (8 waves: row-half rh x key-quarter kq), 64-key
// chunks, ONE barrier/chunk (dbuf P), max-only pass 0, l deferred to pass 1
// (epilogue divide), K prefetch + pre-barrier V loads. proj: load-grouped.
// MFMA 16x16x32_bf16 layouts (HW-verified): A[m=lane&15][k=quad*8+j],
// B[n=lane&15][k=quad*8+j], C/D: col=lane&15, row=quad*4+reg.

#define CH  256
#define DQ  32
#define NSP 4096
#define RWS 320

typedef short short8 __attribute__((ext_vector_type(8)));
typedef float float4v __attribute__((ext_vector_type(4)));

__device__ __forceinline__ unsigned short f2b(float f) {  // RNE f32->bf16
  unsigned int u = __float_as_uint(f);
  unsigned int r = u + 0x7fffu + ((u >> 16) & 1u);
  return (unsigned short)(r >> 16);
}
__device__ __forceinline__ short8 ld8(const unsigned short* p) {
  return *(const short8*)p;
}

// ---------------------------------------------------------------- prep ------
__global__ __launch_bounds__(256) void prep_kernel(
    const float* __restrict__ wq, const float* __restrict__ bq,
    const float* __restrict__ wk, const float* __restrict__ bk,
    const float* __restrict__ wv, const float* __restrict__ bv,
    float* __restrict__ wall, float* __restrict__ ball) {
  int r = blockIdx.x, c = threadIdx.x;
  float v;
  if (r < 32)       v = wq[r * CH + c];
  else if (r < 64)  v = wk[(r - 32) * CH + c];
  else              v = wv[(r - 64) * CH + c];
  wall[r * CH + c] = v;
  if (c == 0)
    ball[r] = (r < 32) ? bq[r] : (r < 64 ? bk[r - 32] : bv[r - 64]);
}

// ---------------------------------------------------------------- proj ------
// grid (64, 2, ns); block 256. Block: 160 rows x 64 n; thread 10 rows x 4 n.
// All 14 loads of a c4-iteration grouped up front for MLP.
__global__ __launch_bounds__(256, 4) void proj_kernel(
    const float* __restrict__ x,
    const float* __restrict__ wall, const float* __restrict__ ball,
    unsigned short* __restrict__ qb, unsigned short* __restrict__ kb,
    unsigned short* __restrict__ vb, int b0) {
  const int bz = blockIdx.z;
  const int bg = b0 + bz;
  const int t  = threadIdx.x;
  const int r0 = blockIdx.y * 160 + (t >> 4) * 10;
  const int n  = blockIdx.x * 64 + (t & 15) * 4;
  const float* xp = x + (size_t)bg * CH * NSP + n;

  float acc[10][4];
#pragma unroll
  for (int rr = 0; rr < 10; ++rr) {
    float bias = ball[r0 + rr];
#pragma unroll
    for (int nn = 0; nn < 4; ++nn) acc[rr][nn] = bias;
  }

#pragma unroll 1
  for (int c4 = 0; c4 < CH; c4 += 4) {
    float4 xv[4];
    float4 wr[10];
#pragma unroll
    for (int cc = 0; cc < 4; ++cc)
      xv[cc] = *(const float4*)(xp + (size_t)(c4 + cc) * NSP);
#pragma unroll
    for (int rr = 0; rr < 10; ++rr)
      wr[rr] = *(const float4*)(wall + (size_t)(r0 + rr) * CH + c4);
#pragma unroll
    for (int rr = 0; rr < 10; ++rr) {
      acc[rr][0] += wr[rr].x * xv[0].x + wr[rr].y * xv[1].x + wr[rr].z * xv[2].x + wr[rr].w * xv[3].x;
      acc[rr][1] += wr[rr].x * xv[0].y + wr[rr].y * xv[1].y + wr[rr].z * xv[2].y + wr[rr].w * xv[3].y;
      acc[rr][2] += wr[rr].x * xv[0].z + wr[rr].y * xv[1].z + wr[rr].z * xv[2].z + wr[rr].w * xv[3].z;
      acc[rr][3] += wr[rr].x * xv[0].w + wr[rr].y * xv[1].w + wr[rr].z * xv[2].w + wr[rr].w * xv[3].w;
    }
  }

#pragma unroll
  for (int rr = 0; rr < 10; ++rr) {
    int r = r0 + rr;
    if (r < 32) {
#pragma unroll
      for (int nn = 0; nn < 4; ++nn)
        qb[((size_t)bz * NSP + n + nn) * DQ + r] = f2b(acc[rr][nn]);
    } else if (r < 64) {
#pragma unroll
      for (int nn = 0; nn < 4; ++nn)
        kb[((size_t)bz * NSP + n + nn) * DQ + (r - 32)] = f2b(acc[rr][nn]);
    } else {
      ushort4 o = {f2b(acc[rr][0]), f2b(acc[rr][1]), f2b(acc[rr][2]), f2b(acc[rr][3])};
      *(ushort4*)&vb[((size_t)bz * CH + (r - 64)) * NSP + n] = o;
    }
  }
}

// ---------------------------------------------------------------- attn ------
// grid (64*ns) of 512 threads (8 waves). bl = blockIdx%ns (XCD-pins batch);
// i0 = (blockIdx/ns)*64. Wave w: rh=w>>2 (rows 32rh..+32), kq=w&3 (keys
// 16kq..+16 of each 64-key chunk) for QK/softmax; channels 32w..+32 for PV.
// Pass 0: max-only (8 fmax/chunk), quad-shuffle + LDS merge -> moff.
// Pass 1 per 64-key chunk: QK (2 MFMA) -> p=exp2(s*LOG2E-moff), lp+=p,
// P bf16 -> LDS dbuf -> ONE barrier -> 8 pf ds_reads + 16 PV MFMAs
// (V loads issued pre-barrier). Epilogue: reduce lp -> l, divide, +x, store.
__global__ __launch_bounds__(512, 4) void attn_kernel(
    const float* __restrict__ x,
    const unsigned short* __restrict__ qb, const unsigned short* __restrict__ kb,
    const unsigned short* __restrict__ vb,
    float* __restrict__ out, int b0, int ns) {
  __shared__ unsigned short ps[2][64][72];  // P bf16 dbuf, row stride 144 B
  __shared__ float buf[4][64];              // per-kq m / l partials
  __shared__ float lf[64];                  // 1/l per row

  const int bl   = blockIdx.x % ns;
  const int bg   = b0 + bl;
  const int i0   = (blockIdx.x / ns) * 64;
  const int t    = threadIdx.x;
  const int w    = t >> 6;
  const int rh   = w >> 2;
  const int kq   = w & 3;
  const int lane = t & 63;
  const int col  = lane & 15;
  const int quad = lane >> 4;
  const float LOG2E = 1.4426950408889634f;

  const unsigned short* qbb = qb + (size_t)bl * NSP * DQ;
  const unsigned short* kbb = kb + (size_t)bl * NSP * DQ;
  const unsigned short* vbb = vb + (size_t)bl * CH * NSP;

  short8 qf[2];
#pragma unroll
  for (int rgp = 0; rgp < 2; ++rgp)
    qf[rgp] = ld8(qbb + (size_t)(i0 + 32 * rh + 16 * rgp + col) * DQ + quad * 8);
  const float4v z4 = (float4v){0.f, 0.f, 0.f, 0.f};

  // ---------------- pass 0: max only ----------------
  float m_[2][4];
#pragma unroll
  for (int rgp = 0; rgp < 2; ++rgp)
#pragma unroll
    for (int reg = 0; reg < 4; ++reg) m_[rgp][reg] = -3.0e38f;

  short8 kf = ld8(kbb + (size_t)(16 * kq + col) * DQ + quad * 8);
  for (int j0 = 0; j0 < NSP; j0 += 64) {
    int jn = (j0 + 64 < NSP) ? j0 + 64 : 0;
    short8 kfn = ld8(kbb + (size_t)(jn + 16 * kq + col) * DQ + quad * 8);
    float4v c0 = __builtin_amdgcn_mfma_f32_16x16x32_bf16(qf[0], kf, z4, 0, 0, 0);
    float4v c1 = __builtin_amdgcn_mfma_f32_16x16x32_bf16(qf[1], kf, z4, 0, 0, 0);
#pragma unroll
    for (int reg = 0; reg < 4; ++reg) {
      m_[0][reg] = fmaxf(m_[0][reg], c0[reg]);
      m_[1][reg] = fmaxf(m_[1][reg], c1[reg]);
    }
    kf = kfn;
  }
#pragma unroll
  for (int rgp = 0; rgp < 2; ++rgp)
#pragma unroll
    for (int reg = 0; reg < 4; ++reg) {
#pragma unroll
      for (int mask = 1; mask <= 8; mask <<= 1)
        m_[rgp][reg] = fmaxf(m_[rgp][reg], __shfl_xor(m_[rgp][reg], mask));
    }
  if (col == 0) {
#pragma unroll
    for (int rgp = 0; rgp < 2; ++rgp)
#pragma unroll
      for (int reg = 0; reg < 4; ++reg)
        buf[kq][32 * rh + 16 * rgp + quad * 4 + reg] = m_[rgp][reg];
  }
  __syncthreads();
  float moff[2][4];
#pragma unroll
  for (int rgp = 0; rgp < 2; ++rgp)
#pragma unroll
    for (int reg = 0; reg < 4; ++reg) {
      int row = 32 * rh + 16 * rgp + quad * 4 + reg;
      float m = fmaxf(fmaxf(buf[0][row], buf[1][row]),
                      fmaxf(buf[2][row], buf[3][row]));
      moff[rgp][reg] = m * LOG2E;
    }
  __syncthreads();

  // ---------------- pass 1: P + PV, deferred l ----------------
  float4v acc[4][2];  // [row-group 16][channel-tile]
#pragma unroll
  for (int rg = 0; rg < 4; ++rg)
#pragma unroll
    for (int ct = 0; ct < 2; ++ct) acc[rg][ct] = z4;
  float lp[2][4];
#pragma unroll
  for (int rgp = 0; rgp < 2; ++rgp)
#pragma unroll
    for (int reg = 0; reg < 4; ++reg) lp[rgp][reg] = 0.0f;

  kf = ld8(kbb + (size_t)(16 * kq + col) * DQ + quad * 8);
  for (int j0 = 0; j0 < NSP; j0 += 64) {
    const int cp = (j0 >> 6) & 1;
    // V fragments for this chunk (consumed after the barrier)
    short8 vf[2][2];
#pragma unroll
    for (int ct = 0; ct < 2; ++ct)
#pragma unroll
      for (int h = 0; h < 2; ++h)
        vf[ct][h] = ld8(vbb + (size_t)(32 * w + 16 * ct + col) * NSP
                        + j0 + 32 * h + quad * 8);
    float4v c0 = __builtin_amdgcn_mfma_f32_16x16x32_bf16(qf[0], kf, z4, 0, 0, 0);
    float4v c1 = __builtin_amdgcn_mfma_f32_16x16x32_bf16(qf[1], kf, z4, 0, 0, 0);
    int jn = (j0 + 64 < NSP) ? j0 + 64 : 0;
    short8 kfn = ld8(kbb + (size_t)(jn + 16 * kq + col) * DQ + quad * 8);
#pragma unroll
    for (int reg = 0; reg < 4; ++reg) {
      float p0 = __builtin_amdgcn_exp2f(fmaf(c0[reg], LOG2E, -moff[0][reg]));
      float p1 = __builtin_amdgcn_exp2f(fmaf(c1[reg], LOG2E, -moff[1][reg]));
      lp[0][reg] += p0;
      lp[1][reg] += p1;
      ps[cp][32 * rh + quad * 4 + reg][16 * kq + col]      = f2b(p0);
      ps[cp][32 * rh + 16 + quad * 4 + reg][16 * kq + col] = f2b(p1);
    }
    __syncthreads();   // P(cp) visible; buf-cp readers from 2 chunks ago done

#pragma unroll
    for (int rg = 0; rg < 4; ++rg) {
      short8 pf0 = *(const short8*)&ps[cp][16 * rg + col][quad * 8];
      short8 pf1 = *(const short8*)&ps[cp][16 * rg + col][32 + quad * 8];
#pragma unroll
      for (int ct = 0; ct < 2; ++ct) {
        acc[rg][ct] = __builtin_amdgcn_mfma_f32_16x16x32_bf16(pf0, vf[ct][0], acc[rg][ct], 0, 0, 0);
        acc[rg][ct] = __builtin_amdgcn_mfma_f32_16x16x32_bf16(pf1, vf[ct][1], acc[rg][ct], 0, 0, 0);
      }
    }
    kf = kfn;
  }

  // ---------------- l reduction ----------------
#pragma unroll
  for (int rgp = 0; rgp < 2; ++rgp)
#pragma unroll
    for (int reg = 0; reg < 4; ++reg) {
#pragma unroll
      for (int mask = 1; mask <= 8; mask <<= 1)
        lp[rgp][reg] += __shfl_xor(lp[rgp][reg], mask);
    }
  if (col == 0) {
#pragma unroll
    for (int rgp = 0; rgp < 2; ++rgp)
#pragma unroll
      for (int reg = 0; reg < 4; ++reg)
        buf[kq][32 * rh + 16 * rgp + quad * 4 + reg] = lp[rgp][reg];
  }
  __syncthreads();
  if (kq == 0 && col == 0) {
#pragma unroll
    for (int rgp = 0; rgp < 2; ++rgp)
#pragma unroll
      for (int reg = 0; reg < 4; ++reg) {
        int row = 32 * rh + 16 * rgp + quad * 4 + reg;
        lf[row] = 1.0f / (buf[0][row] + buf[1][row] + buf[2][row] + buf[3][row]);
      }
  }
  __syncthreads();

  // ---------------- epilogue: normalize + residual + store ----------------
#pragma unroll
  for (int rg = 0; rg < 4; ++rg) {
    float linv[4];
#pragma unroll
    for (int reg = 0; reg < 4; ++reg)
      linv[reg] = lf[16 * rg + quad * 4 + reg];
#pragma unroll
    for (int ct = 0; ct < 2; ++ct) {
      int c  = 32 * w + 16 * ct + col;
      int ib = i0 + 16 * rg + quad * 4;
      size_t idx = ((size_t)bg * CH + c) * NSP + ib;
      float4 xr = *(const float4*)&x[idx];
      float4 o;
      o.x = acc[rg][ct][0] * linv[0] + xr.x;
      o.y = acc[rg][ct][1] * linv[1] + xr.y;
      o.z = acc[rg][ct][2] * linv[2] + xr.z;
      o.w = acc[rg][ct][3] * linv[3] + xr.w;
      *(float4*)&out[idx] = o;
    }
  }
}

// ---------------------------------------------------------------- launch ----
extern "C" void kernel_launch(void* const* d_in, const int* in_sizes, int n_in,
                              void* d_out, int out_size, void* d_ws, size_t ws_size,
                              hipStream_t stream) {
  (void)in_sizes; (void)n_in; (void)out_size;
  const float* x  = (const float*)d_in[0];
  const float* wq = (const float*)d_in[1];
  const float* bq = (const float*)d_in[2];
  const float* wk = (const float*)d_in[3];
  const float* bk = (const float*)d_in[4];
  const float* wv = (const float*)d_in[5];
  const float* bv = (const float*)d_in[6];
  float* out = (float*)d_out;

  const size_t WALL_B = (size_t)RWS * CH * sizeof(float) + 4096;  // wall+ball
  const size_t QB_B = (size_t)NSP * DQ * sizeof(unsigned short);  // 256 KiB
  const size_t VB_B = (size_t)CH * NSP * sizeof(unsigned short);  //   2 MiB
  const size_t PER_B = 2 * QB_B + VB_B;                           // 2.5 MiB/batch

  int ns = 8;
  while (ns > 1 && WALL_B + (size_t)ns * PER_B > ws_size) ns >>= 1;

  char* ws = (char*)d_ws;
  float* wall = (float*)ws;
  float* ball = (float*)(ws + (size_t)RWS * CH * sizeof(float));
  char* qkv = ws + WALL_B;
  unsigned short* qb = (unsigned short*)qkv;
  unsigned short* kb = (unsigned short*)(qkv + (size_t)ns * QB_B);
  unsigned short* vb = (unsigned short*)(qkv + (size_t)ns * 2 * QB_B);

  prep_kernel<<<dim3(RWS), dim3(256), 0, stream>>>(wq, bq, wk, bk, wv, bv, wall, ball);
  for (int b0 = 0; b0 < 8; b0 += ns) {
    proj_kernel<<<dim3(64, 2, ns), dim3(256), 0, stream>>>(
        x, wall, ball, qb, kb, vb, b0);
    attn_kernel<<<dim3(64 * ns), dim3(512), 0, stream>>>(
        x, qb, kb, vb, out, b0, ns);
  }
}